// Round 4
// baseline (343.745 us; speedup 1.0000x reference)
//
#include <hip/hip_runtime.h>

// Raymarcher: R=16384 rays, 64 steps, K=32 prims, template (32,4,16,16,16) f32.
// Round 4: work compaction. Per (ray,prim), the inside region is a contiguous
// integer step range [i0,i1] (slab intervals). Block = 8 rays x 32 prim-lanes;
// per-ray item list (Sum len items) built via shuffle scan; lanes process items
// round-robin (binary search item->prim) so trilinear runs at ~full lane
// utilization. Samples accumulate into per-(ray,step) LDS buckets (ds_add_f32).
// Composite via exact prefix-scan (increments >= 0 -> iterated clip == min(prefix,1)).

namespace {

constexpr float kDT  = 1.0f / 64.0f;
constexpr int   kVox = 32 * 4096;   // (k,z,y,x) voxel count
constexpr int   RPB  = 8;           // rays per block (256 threads = 8 x 32)

// ---- pre-pass: (k,c,z,y,x) -> (k,z,y,x,c) channel-last ----
__global__ __launch_bounds__(256) void transpose_tmpl(
    const float* __restrict__ tmpl, float* __restrict__ wsT)
{
    const int idx = blockIdx.x * 256 + threadIdx.x;     // < 131072
    const int k   = idx >> 12;
    const int rem = idx & 4095;
    const float* src = tmpl + k * 16384 + rem;
    float4 v;
    v.x = src[0];
    v.y = src[4096];
    v.z = src[8192];
    v.w = src[12288];
    ((float4*)wsT)[idx] = v;
}

template <bool T4>
__global__ __launch_bounds__(256) void raymarch3(
    const float* __restrict__ raypos,
    const float* __restrict__ raydir,
    const float* __restrict__ tminmax,
    const float* __restrict__ primpos,
    const float* __restrict__ primrot,
    const float* __restrict__ primscale,
    const float* __restrict__ tmpl,      // original layout (fallback)
    const float* __restrict__ tmplT,     // channel-last layout
    float* __restrict__ out,
    int R)
{
    const int lane = threadIdx.x & 63;
    const int wid  = threadIdx.x >> 6;          // wave 0..3
    const int sub  = lane & 31;                 // prim index
    const int rl   = wid * 2 + (lane >> 5);     // ray-in-block 0..7
    const int ray  = blockIdx.x * RPB + rl;

    __shared__ float4 sA[RPB][32];              // a.xyz
    __shared__ float4 sD[RPB][32];              // d.xyz
    __shared__ float  sAcc[RPB][64][4];         // per (ray,step) samp sums
    __shared__ int    sOff[RPB][33];            // item offsets per prim (+pad)
    __shared__ int    sI0[RPB][32];             // first step per prim

    // zero the accumulation buckets (ws/LDS are poisoned)
    {
        float* p = &sAcc[0][0][0];
        #pragma unroll
        for (int i = 0; i < (RPB * 64 * 4) / 256; ++i)
            p[threadIdx.x + 256 * i] = 0.0f;
    }

    const float rpx = raypos[ray * 3 + 0];
    const float rpy = raypos[ray * 3 + 1];
    const float rpz = raypos[ray * 3 + 2];
    const float rdx = raydir[ray * 3 + 0];
    const float rdy = raydir[ray * 3 + 1];
    const float rdz = raydir[ray * 3 + 2];
    const float tmin = tminmax[ray * 2 + 0];
    const float tmax = tminmax[ray * 2 + 1];

    // last valid step: largest i in [0,63] with tmin + i*DT < tmax
    int last = min(63, (int)floorf((tmax - tmin) * 64.0f));
    if (last >= 0 && fmaf((float)last, kDT, tmin) >= tmax) last--;

    // per-(ray,prim) affine + step range (slab widened 1.001; exact test later)
    int i0, len;
    {
        const int k = sub;
        const float ox = rpx - primpos[k * 3 + 0];
        const float oy = rpy - primpos[k * 3 + 1];
        const float oz = rpz - primpos[k * 3 + 2];
        float a[3], d[3];
        float lo = -1e30f, hi = 1e30f;
        #pragma unroll
        for (int i = 0; i < 3; ++i) {
            const float r0 = primrot[k * 9 + 3 * i + 0];
            const float r1 = primrot[k * 9 + 3 * i + 1];
            const float r2 = primrot[k * 9 + 3 * i + 2];
            const float sci = primscale[k * 3 + i];
            a[i] = (r0 * ox + r1 * oy + r2 * oz) * sci;
            d[i] = (r0 * rdx + r1 * rdy + r2 * rdz) * sci;
            const float inv = 1.0f / d[i];
            const float tA = (-1.001f - a[i]) * inv;
            const float tB = ( 1.001f - a[i]) * inv;
            lo = fmaxf(lo, fminf(tA, tB));
            hi = fminf(hi, fmaxf(tA, tB));
        }
        i0 = max(0,    (int)ceilf ((lo - tmin) * 64.0f));
        const int i1 = min(last, (int)floorf((hi - tmin) * 64.0f));
        len = max(0, i1 - i0 + 1);
        sA[rl][k] = make_float4(a[0], a[1], a[2], 0.0f);
        sD[rl][k] = make_float4(d[0], d[1], d[2], 0.0f);
    }

    // 32-lane inclusive scan of len (half-wave local: shfl_up sources stay in half)
    int psum = len;
    #pragma unroll
    for (int m = 1; m < 32; m <<= 1) {
        const int n = __shfl_up(psum, m);
        if (sub >= m) psum += n;
    }
    const int off   = psum - len;
    const int total = __shfl(psum, lane | 31);   // inclusive sum at sub==31 of own half
    sOff[rl][sub] = off;
    sI0[rl][sub]  = i0;
    __syncthreads();

    // balanced item loop: item j of this ray -> (prim kk, step)
    for (int j = sub; j < total; j += 32) {
        int lo_ = 0, hi_ = 31;
        #pragma unroll
        for (int s = 0; s < 5; ++s) {
            const int mid = (lo_ + hi_ + 1) >> 1;
            if (sOff[rl][mid] <= j) lo_ = mid; else hi_ = mid - 1;
        }
        const int kk   = lo_;
        const int step = sI0[rl][kk] + (j - sOff[rl][kk]);
        const float t  = fmaf((float)step, kDT, tmin);
        const float4 A = sA[rl][kk];
        const float4 D = sD[rl][kk];
        const float y0 = fmaf(D.x, t, A.x);
        const float y1 = fmaf(D.y, t, A.y);
        const float y2 = fmaf(D.z, t, A.z);
        if (fabsf(y0) <= 1.0f && fabsf(y1) <= 1.0f && fabsf(y2) <= 1.0f) {
            const float gz = (y0 + 1.0f) * 7.5f;
            const float gy = (y1 + 1.0f) * 7.5f;
            const float gx = (y2 + 1.0f) * 7.5f;
            const int iz = (int)fminf(floorf(gz), 14.0f);
            const int iy = (int)fminf(floorf(gy), 14.0f);
            const int ix = (int)fminf(floorf(gx), 14.0f);
            const float fz = fminf(gz - (float)iz, 1.0f);
            const float fy = fminf(gy - (float)iy, 1.0f);
            const float fx = fminf(gx - (float)ix, 1.0f);
            const float oz_ = 1.0f - fz, oy_ = 1.0f - fy, ox_ = 1.0f - fx;
            const float w000 = oz_ * oy_ * ox_;
            const float w001 = oz_ * oy_ * fx;
            const float w010 = oz_ * fy  * ox_;
            const float w011 = oz_ * fy  * fx;
            const float w100 = fz  * oy_ * ox_;
            const float w101 = fz  * oy_ * fx;
            const float w110 = fz  * fy  * ox_;
            const float w111 = fz  * fy  * fx;
            float v0, v1, v2, v3;
            if (T4) {
                const float* tp = tmplT + ((kk * 4096 + iz * 256 + iy * 16 + ix) << 2);
                const float4 c000 = *(const float4*)(tp + 0);
                const float4 c001 = *(const float4*)(tp + 4);
                const float4 c010 = *(const float4*)(tp + 64);
                const float4 c011 = *(const float4*)(tp + 68);
                const float4 c100 = *(const float4*)(tp + 1024);
                const float4 c101 = *(const float4*)(tp + 1028);
                const float4 c110 = *(const float4*)(tp + 1088);
                const float4 c111 = *(const float4*)(tp + 1092);
                v0 = w000*c000.x + w001*c001.x + w010*c010.x + w011*c011.x
                   + w100*c100.x + w101*c101.x + w110*c110.x + w111*c111.x;
                v1 = w000*c000.y + w001*c001.y + w010*c010.y + w011*c011.y
                   + w100*c100.y + w101*c101.y + w110*c110.y + w111*c111.y;
                v2 = w000*c000.z + w001*c001.z + w010*c010.z + w011*c011.z
                   + w100*c100.z + w101*c101.z + w110*c110.z + w111*c111.z;
                v3 = w000*c000.w + w001*c001.w + w010*c010.w + w011*c011.w
                   + w100*c100.w + w101*c101.w + w110*c110.w + w111*c111.w;
            } else {
                const float* tp = tmpl + kk * 16384 + iz * 256 + iy * 16 + ix;
                float acc[4];
                #pragma unroll
                for (int c = 0; c < 4; ++c) {
                    const float* tc = tp + c * 4096;
                    acc[c] = w000 * tc[0]   + w001 * tc[1]
                           + w010 * tc[16]  + w011 * tc[17]
                           + w100 * tc[256] + w101 * tc[257]
                           + w110 * tc[272] + w111 * tc[273];
                }
                v0 = acc[0]; v1 = acc[1]; v2 = acc[2]; v3 = acc[3];
            }
            atomicAdd(&sAcc[rl][step][0], v0);
            atomicAdd(&sAcc[rl][step][1], v1);
            atomicAdd(&sAcc[rl][step][2], v2);
            atomicAdd(&sAcc[rl][step][3], v3);
        }
    }
    __syncthreads();

    // composite: lane = step; exact prefix-scan alpha
    #pragma unroll
    for (int rr = 0; rr < 2; ++rr) {
        const int rl2  = wid * 2 + rr;
        const int ray2 = blockIdx.x * RPB + rl2;
        const float tmn = tminmax[ray2 * 2 + 0];
        const float tmx = tminmax[ray2 * 2 + 1];
        const float t2  = fmaf((float)lane, kDT, tmn);
        const float4 v  = *(const float4*)&sAcc[rl2][lane][0];
        const float a   = v.w * kDT * ((t2 < tmx) ? 1.0f : 0.0f);
        float psum2 = a;
        #pragma unroll
        for (int m = 1; m < 64; m <<= 1) {
            const float n = __shfl_up(psum2, m);
            if (lane >= m) psum2 += n;
        }
        const float alpha_i    = fminf(psum2, 1.0f);
        const float alpha_prev = fminf(psum2 - a, 1.0f);
        const float contrib    = alpha_i - alpha_prev;
        float r0 = v.x * contrib;
        float r1 = v.y * contrib;
        float r2 = v.z * contrib;
        #pragma unroll
        for (int m = 1; m < 64; m <<= 1) {
            r0 += __shfl_xor(r0, m);
            r1 += __shfl_xor(r1, m);
            r2 += __shfl_xor(r2, m);
        }
        const float alpha_end = __shfl(alpha_i, 63);
        if (lane == 0) {
            out[0 * R + ray2] = r0;
            out[1 * R + ray2] = r1;
            out[2 * R + ray2] = r2;
            out[3 * R + ray2] = alpha_end;
            out[4 * R + ray2] = r0;
            out[5 * R + ray2] = r1;
            out[6 * R + ray2] = r2;
            out[7 * R + ray2] = alpha_end;
        }
    }
}

} // namespace

extern "C" void kernel_launch(void* const* d_in, const int* in_sizes, int n_in,
                              void* d_out, int out_size, void* d_ws, size_t ws_size,
                              hipStream_t stream) {
    const float* raypos    = (const float*)d_in[0];
    const float* raydir    = (const float*)d_in[1];
    const float* tminmax   = (const float*)d_in[2];
    const float* primpos   = (const float*)d_in[3];
    const float* primrot   = (const float*)d_in[4];
    const float* primscale = (const float*)d_in[5];
    const float* tmpl      = (const float*)d_in[6];
    float* out = (float*)d_out;

    const int R = in_sizes[0] / 3;   // 16384
    const size_t tmplBytes = (size_t)kVox * 4 * sizeof(float);  // 2 MiB

    if (ws_size >= tmplBytes) {
        float* wsT = (float*)d_ws;
        transpose_tmpl<<<dim3(kVox / 256), dim3(256), 0, stream>>>(tmpl, wsT);
        raymarch3<true><<<dim3(R / RPB), dim3(256), 0, stream>>>(
            raypos, raydir, tminmax, primpos, primrot, primscale, tmpl, wsT, out, R);
    } else {
        raymarch3<false><<<dim3(R / RPB), dim3(256), 0, stream>>>(
            raypos, raydir, tminmax, primpos, primrot, primscale, tmpl, nullptr, out, R);
    }
}

// Round 5
// 103.271 us; speedup vs baseline: 3.3286x; 3.3286x over previous
//
#include <hip/hip_runtime.h>

// Raymarcher: R=16384 rays, 64 steps, K=32 prims, template (32,4,16,16,16) f32.
// Round 5: round-1 structure with 4x parallelism. 32 threads/ray, 1 prim/lane
// (2048 blocks x 256 = 32 waves/CU). Exact per-lane inside test (3 fma+3 cmp),
// channel-last template -> 8 independent float4 corner loads, 5-stage half-wave
// shfl_xor reduce per step, ballot-skip of empty steps, ballot-break when all
// rays done. Alpha update exact vs reference (salpha >= 0, clip == min).

namespace {

constexpr float kDT  = 1.0f / 64.0f;
constexpr int   kVox = 32 * 4096;   // (k,z,y,x) voxel count

// ---- pre-pass: (k,c,z,y,x) -> (k,z,y,x,c) channel-last ----
__global__ __launch_bounds__(256) void transpose_tmpl(
    const float* __restrict__ tmpl, float* __restrict__ wsT)
{
    const int idx = blockIdx.x * 256 + threadIdx.x;     // < 131072
    const int k   = idx >> 12;
    const int rem = idx & 4095;
    const float* src = tmpl + k * 16384 + rem;
    float4 v;
    v.x = src[0];
    v.y = src[4096];
    v.z = src[8192];
    v.w = src[12288];
    ((float4*)wsT)[idx] = v;
}

template <bool T4>
__global__ __launch_bounds__(256) void raymarch4(
    const float* __restrict__ raypos,
    const float* __restrict__ raydir,
    const float* __restrict__ tminmax,
    const float* __restrict__ primpos,
    const float* __restrict__ primrot,
    const float* __restrict__ primscale,
    const float* __restrict__ tmpl,      // original layout (fallback)
    const float* __restrict__ tmplT,     // channel-last layout
    float* __restrict__ out,
    int R)
{
    const int lane = threadIdx.x & 63;
    const int wid  = threadIdx.x >> 6;          // wave 0..3
    const int k    = lane & 31;                 // prim owned by this lane
    const int half = lane >> 5;                 // ray within wave
    const int ray  = blockIdx.x * 8 + wid * 2 + half;

    const float rpx = raypos[ray * 3 + 0];
    const float rpy = raypos[ray * 3 + 1];
    const float rpz = raypos[ray * 3 + 2];
    const float rdx = raydir[ray * 3 + 0];
    const float rdy = raydir[ray * 3 + 1];
    const float rdz = raydir[ray * 3 + 2];
    const float tmin = tminmax[ray * 2 + 0];
    const float tmax = tminmax[ray * 2 + 1];

    // Fold prim k into affine y_i(t) = A_i + D_i * t  (exact same products as
    // reference up to fma rounding; verified absmax 0.031 in rounds 3/4).
    float A0, A1, A2, D0, D1, D2;
    {
        const float ox = rpx - primpos[k * 3 + 0];
        const float oy = rpy - primpos[k * 3 + 1];
        const float oz = rpz - primpos[k * 3 + 2];
        const float s0 = primscale[k * 3 + 0];
        const float s1 = primscale[k * 3 + 1];
        const float s2 = primscale[k * 3 + 2];
        const float* rk = primrot + k * 9;
        A0 = (rk[0] * ox + rk[1] * oy + rk[2] * oz) * s0;
        D0 = (rk[0] * rdx + rk[1] * rdy + rk[2] * rdz) * s0;
        A1 = (rk[3] * ox + rk[4] * oy + rk[5] * oz) * s1;
        D1 = (rk[3] * rdx + rk[4] * rdy + rk[5] * rdz) * s1;
        A2 = (rk[6] * ox + rk[7] * oy + rk[8] * oz) * s2;
        D2 = (rk[6] * rdx + rk[7] * rdy + rk[8] * rdz) * s2;
    }

    float alpha = 0.f, r0 = 0.f, r1 = 0.f, r2 = 0.f;

    for (int i = 0; i < 64; ++i) {
        const float t = fmaf((float)i, kDT, tmin);
        const bool live = (t < tmax) && (alpha < 1.0f);
        if (__ballot(live) == 0ull) break;

        const float y0 = fmaf(D0, t, A0);
        const float y1 = fmaf(D1, t, A1);
        const float y2 = fmaf(D2, t, A2);
        const bool inside = live && fabsf(y0) <= 1.0f && fabsf(y1) <= 1.0f
                                 && fabsf(y2) <= 1.0f;
        if (__ballot(inside) == 0ull) continue;   // s==0 -> contrib==0, skip all

        float s0 = 0.f, s1 = 0.f, s2 = 0.f, s3 = 0.f;
        if (inside) {
            const float gz = (y0 + 1.0f) * 7.5f;
            const float gy = (y1 + 1.0f) * 7.5f;
            const float gx = (y2 + 1.0f) * 7.5f;
            const int iz = (int)fminf(floorf(gz), 14.0f);
            const int iy = (int)fminf(floorf(gy), 14.0f);
            const int ix = (int)fminf(floorf(gx), 14.0f);
            const float fz = fminf(gz - (float)iz, 1.0f);
            const float fy = fminf(gy - (float)iy, 1.0f);
            const float fx = fminf(gx - (float)ix, 1.0f);
            const float oz_ = 1.0f - fz, oy_ = 1.0f - fy, ox_ = 1.0f - fx;
            const float w000 = oz_ * oy_ * ox_;
            const float w001 = oz_ * oy_ * fx;
            const float w010 = oz_ * fy  * ox_;
            const float w011 = oz_ * fy  * fx;
            const float w100 = fz  * oy_ * ox_;
            const float w101 = fz  * oy_ * fx;
            const float w110 = fz  * fy  * ox_;
            const float w111 = fz  * fy  * fx;
            if (T4) {
                const float* tp = tmplT + ((k * 4096 + iz * 256 + iy * 16 + ix) << 2);
                const float4 c000 = *(const float4*)(tp + 0);
                const float4 c001 = *(const float4*)(tp + 4);
                const float4 c010 = *(const float4*)(tp + 64);
                const float4 c011 = *(const float4*)(tp + 68);
                const float4 c100 = *(const float4*)(tp + 1024);
                const float4 c101 = *(const float4*)(tp + 1028);
                const float4 c110 = *(const float4*)(tp + 1088);
                const float4 c111 = *(const float4*)(tp + 1092);
                s0 = w000*c000.x + w001*c001.x + w010*c010.x + w011*c011.x
                   + w100*c100.x + w101*c101.x + w110*c110.x + w111*c111.x;
                s1 = w000*c000.y + w001*c001.y + w010*c010.y + w011*c011.y
                   + w100*c100.y + w101*c101.y + w110*c110.y + w111*c111.y;
                s2 = w000*c000.z + w001*c001.z + w010*c010.z + w011*c011.z
                   + w100*c100.z + w101*c101.z + w110*c110.z + w111*c111.z;
                s3 = w000*c000.w + w001*c001.w + w010*c010.w + w011*c011.w
                   + w100*c100.w + w101*c101.w + w110*c110.w + w111*c111.w;
            } else {
                const float* tp = tmpl + k * 16384 + iz * 256 + iy * 16 + ix;
                float acc[4];
                #pragma unroll
                for (int c = 0; c < 4; ++c) {
                    const float* tc = tp + c * 4096;
                    acc[c] = w000 * tc[0]   + w001 * tc[1]
                           + w010 * tc[16]  + w011 * tc[17]
                           + w100 * tc[256] + w101 * tc[257]
                           + w110 * tc[272] + w111 * tc[273];
                }
                s0 = acc[0]; s1 = acc[1]; s2 = acc[2]; s3 = acc[3];
            }
        }

        // Reduce across the 32 lanes of this ray (xor masks < 32 stay in half).
        #pragma unroll
        for (int m = 1; m < 32; m <<= 1) {
            s0 += __shfl_xor(s0, m);
            s1 += __shfl_xor(s1, m);
            s2 += __shfl_xor(s2, m);
            s3 += __shfl_xor(s3, m);
        }

        const float na = fminf(fmaf(s3, kDT, alpha), 1.0f);  // s3 >= 0
        const float contrib = na - alpha;
        r0 = fmaf(s0, contrib, r0);
        r1 = fmaf(s1, contrib, r1);
        r2 = fmaf(s2, contrib, r2);
        alpha = na;
    }

    if (k == 0) {
        out[0 * R + ray] = r0;
        out[1 * R + ray] = r1;
        out[2 * R + ray] = r2;
        out[3 * R + ray] = alpha;
        out[4 * R + ray] = r0;
        out[5 * R + ray] = r1;
        out[6 * R + ray] = r2;
        out[7 * R + ray] = alpha;
    }
}

} // namespace

extern "C" void kernel_launch(void* const* d_in, const int* in_sizes, int n_in,
                              void* d_out, int out_size, void* d_ws, size_t ws_size,
                              hipStream_t stream) {
    const float* raypos    = (const float*)d_in[0];
    const float* raydir    = (const float*)d_in[1];
    const float* tminmax   = (const float*)d_in[2];
    const float* primpos   = (const float*)d_in[3];
    const float* primrot   = (const float*)d_in[4];
    const float* primscale = (const float*)d_in[5];
    const float* tmpl      = (const float*)d_in[6];
    float* out = (float*)d_out;

    const int R = in_sizes[0] / 3;   // 16384
    const size_t tmplBytes = (size_t)kVox * 4 * sizeof(float);  // 2 MiB

    if (ws_size >= tmplBytes) {
        float* wsT = (float*)d_ws;
        transpose_tmpl<<<dim3(kVox / 256), dim3(256), 0, stream>>>(tmpl, wsT);
        raymarch4<true><<<dim3(R / 8), dim3(256), 0, stream>>>(
            raypos, raydir, tminmax, primpos, primrot, primscale, tmpl, wsT, out, R);
    } else {
        raymarch4<false><<<dim3(R / 8), dim3(256), 0, stream>>>(
            raypos, raydir, tminmax, primpos, primrot, primscale, tmpl, nullptr, out, R);
    }
}

// Round 6
// 101.860 us; speedup vs baseline: 3.3747x; 1.0139x over previous
//
#include <hip/hip_runtime.h>

// Raymarcher: R=16384 rays, 64 steps, K=32 prims, template (32,4,16,16,16) f32.
// Round 6: 32 threads/ray, 1 prim/lane, 2048 blocks (32 waves/CU). Per step,
// only the alpha channel is cross-lane reduced (5 shfl); contrib is then
// wave-uniform and rgb accumulates PER-LANE (r += s_rgb*contrib), with one
// final 15-shfl reduce. Same sums reassociated -> 4x fewer shuffle ops than
// round 5 (which spent ~60% of its time on the 20-shfl per-step reduce).

namespace {

constexpr float kDT  = 1.0f / 64.0f;
constexpr int   kVox = 32 * 4096;   // (k,z,y,x) voxel count

// ---- pre-pass: (k,c,z,y,x) -> (k,z,y,x,c) channel-last ----
__global__ __launch_bounds__(256) void transpose_tmpl(
    const float* __restrict__ tmpl, float* __restrict__ wsT)
{
    const int idx = blockIdx.x * 256 + threadIdx.x;     // < 131072
    const int k   = idx >> 12;
    const int rem = idx & 4095;
    const float* src = tmpl + k * 16384 + rem;
    float4 v;
    v.x = src[0];
    v.y = src[4096];
    v.z = src[8192];
    v.w = src[12288];
    ((float4*)wsT)[idx] = v;
}

template <bool T4>
__global__ __launch_bounds__(256) void raymarch5(
    const float* __restrict__ raypos,
    const float* __restrict__ raydir,
    const float* __restrict__ tminmax,
    const float* __restrict__ primpos,
    const float* __restrict__ primrot,
    const float* __restrict__ primscale,
    const float* __restrict__ tmpl,      // original layout (fallback)
    const float* __restrict__ tmplT,     // channel-last layout
    float* __restrict__ out,
    int R)
{
    const int lane = threadIdx.x & 63;
    const int wid  = threadIdx.x >> 6;          // wave 0..3
    const int k    = lane & 31;                 // prim owned by this lane
    const int half = lane >> 5;                 // ray within wave
    const int ray  = blockIdx.x * 8 + wid * 2 + half;

    const float rpx = raypos[ray * 3 + 0];
    const float rpy = raypos[ray * 3 + 1];
    const float rpz = raypos[ray * 3 + 2];
    const float rdx = raydir[ray * 3 + 0];
    const float rdy = raydir[ray * 3 + 1];
    const float rdz = raydir[ray * 3 + 2];
    const float tmin = tminmax[ray * 2 + 0];
    const float tmax = tminmax[ray * 2 + 1];

    // Fold prim k into affine y_i(t) = A_i + D_i * t.
    float A0, A1, A2, D0, D1, D2;
    {
        const float ox = rpx - primpos[k * 3 + 0];
        const float oy = rpy - primpos[k * 3 + 1];
        const float oz = rpz - primpos[k * 3 + 2];
        const float s0 = primscale[k * 3 + 0];
        const float s1 = primscale[k * 3 + 1];
        const float s2 = primscale[k * 3 + 2];
        const float* rk = primrot + k * 9;
        A0 = (rk[0] * ox + rk[1] * oy + rk[2] * oz) * s0;
        D0 = (rk[0] * rdx + rk[1] * rdy + rk[2] * rdz) * s0;
        A1 = (rk[3] * ox + rk[4] * oy + rk[5] * oz) * s1;
        D1 = (rk[3] * rdx + rk[4] * rdy + rk[5] * rdz) * s1;
        A2 = (rk[6] * ox + rk[7] * oy + rk[8] * oz) * s2;
        D2 = (rk[6] * rdx + rk[7] * rdy + rk[8] * rdz) * s2;
    }

    float alpha = 0.f;                 // wave-uniform per half after reduce
    float r0 = 0.f, r1 = 0.f, r2 = 0.f;  // PER-LANE partial rgb

    for (int i = 0; i < 64; ++i) {
        const float t = fmaf((float)i, kDT, tmin);
        const bool live = (t < tmax) && (alpha < 1.0f);
        if (__ballot(live) == 0ull) break;

        const float y0 = fmaf(D0, t, A0);
        const float y1 = fmaf(D1, t, A1);
        const float y2 = fmaf(D2, t, A2);
        const bool inside = live && fabsf(y0) <= 1.0f && fabsf(y1) <= 1.0f
                                 && fabsf(y2) <= 1.0f;
        if (__ballot(inside) == 0ull) continue;   // total==0 -> contrib==0

        float s0 = 0.f, s1 = 0.f, s2 = 0.f, s3 = 0.f;
        if (inside) {
            const float gz = (y0 + 1.0f) * 7.5f;
            const float gy = (y1 + 1.0f) * 7.5f;
            const float gx = (y2 + 1.0f) * 7.5f;
            const int iz = (int)fminf(floorf(gz), 14.0f);
            const int iy = (int)fminf(floorf(gy), 14.0f);
            const int ix = (int)fminf(floorf(gx), 14.0f);
            const float fz = fminf(gz - (float)iz, 1.0f);
            const float fy = fminf(gy - (float)iy, 1.0f);
            const float fx = fminf(gx - (float)ix, 1.0f);
            const float oz_ = 1.0f - fz, oy_ = 1.0f - fy, ox_ = 1.0f - fx;
            const float w000 = oz_ * oy_ * ox_;
            const float w001 = oz_ * oy_ * fx;
            const float w010 = oz_ * fy  * ox_;
            const float w011 = oz_ * fy  * fx;
            const float w100 = fz  * oy_ * ox_;
            const float w101 = fz  * oy_ * fx;
            const float w110 = fz  * fy  * ox_;
            const float w111 = fz  * fy  * fx;
            if (T4) {
                const float* tp = tmplT + ((k * 4096 + iz * 256 + iy * 16 + ix) << 2);
                const float4 c000 = *(const float4*)(tp + 0);
                const float4 c001 = *(const float4*)(tp + 4);
                const float4 c010 = *(const float4*)(tp + 64);
                const float4 c011 = *(const float4*)(tp + 68);
                const float4 c100 = *(const float4*)(tp + 1024);
                const float4 c101 = *(const float4*)(tp + 1028);
                const float4 c110 = *(const float4*)(tp + 1088);
                const float4 c111 = *(const float4*)(tp + 1092);
                s0 = w000*c000.x + w001*c001.x + w010*c010.x + w011*c011.x
                   + w100*c100.x + w101*c101.x + w110*c110.x + w111*c111.x;
                s1 = w000*c000.y + w001*c001.y + w010*c010.y + w011*c011.y
                   + w100*c100.y + w101*c101.y + w110*c110.y + w111*c111.y;
                s2 = w000*c000.z + w001*c001.z + w010*c010.z + w011*c011.z
                   + w100*c100.z + w101*c101.z + w110*c110.z + w111*c111.z;
                s3 = w000*c000.w + w001*c001.w + w010*c010.w + w011*c011.w
                   + w100*c100.w + w101*c101.w + w110*c110.w + w111*c111.w;
            } else {
                const float* tp = tmpl + k * 16384 + iz * 256 + iy * 16 + ix;
                float acc[4];
                #pragma unroll
                for (int c = 0; c < 4; ++c) {
                    const float* tc = tp + c * 4096;
                    acc[c] = w000 * tc[0]   + w001 * tc[1]
                           + w010 * tc[16]  + w011 * tc[17]
                           + w100 * tc[256] + w101 * tc[257]
                           + w110 * tc[272] + w111 * tc[273];
                }
                s0 = acc[0]; s1 = acc[1]; s2 = acc[2]; s3 = acc[3];
            }
        }

        // Only the alpha channel is reduced per step (masks < 32 stay in half).
        float tot3 = s3;
        #pragma unroll
        for (int m = 1; m < 32; m <<= 1) tot3 += __shfl_xor(tot3, m);

        const float na = fminf(fmaf(tot3, kDT, alpha), 1.0f);  // tot3 >= 0
        const float contrib = na - alpha;
        alpha = na;
        // Per-lane rgb accumulation; cross-lane sum deferred to the end.
        r0 = fmaf(s0, contrib, r0);
        r1 = fmaf(s1, contrib, r1);
        r2 = fmaf(s2, contrib, r2);
    }

    // Final cross-lane reduce of the rgb partials (once).
    #pragma unroll
    for (int m = 1; m < 32; m <<= 1) {
        r0 += __shfl_xor(r0, m);
        r1 += __shfl_xor(r1, m);
        r2 += __shfl_xor(r2, m);
    }

    if (k == 0) {
        out[0 * R + ray] = r0;
        out[1 * R + ray] = r1;
        out[2 * R + ray] = r2;
        out[3 * R + ray] = alpha;
        out[4 * R + ray] = r0;
        out[5 * R + ray] = r1;
        out[6 * R + ray] = r2;
        out[7 * R + ray] = alpha;
    }
}

} // namespace

extern "C" void kernel_launch(void* const* d_in, const int* in_sizes, int n_in,
                              void* d_out, int out_size, void* d_ws, size_t ws_size,
                              hipStream_t stream) {
    const float* raypos    = (const float*)d_in[0];
    const float* raydir    = (const float*)d_in[1];
    const float* tminmax   = (const float*)d_in[2];
    const float* primpos   = (const float*)d_in[3];
    const float* primrot   = (const float*)d_in[4];
    const float* primscale = (const float*)d_in[5];
    const float* tmpl      = (const float*)d_in[6];
    float* out = (float*)d_out;

    const int R = in_sizes[0] / 3;   // 16384
    const size_t tmplBytes = (size_t)kVox * 4 * sizeof(float);  // 2 MiB

    if (ws_size >= tmplBytes) {
        float* wsT = (float*)d_ws;
        transpose_tmpl<<<dim3(kVox / 256), dim3(256), 0, stream>>>(tmpl, wsT);
        raymarch5<true><<<dim3(R / 8), dim3(256), 0, stream>>>(
            raypos, raydir, tminmax, primpos, primrot, primscale, tmpl, wsT, out, R);
    } else {
        raymarch5<false><<<dim3(R / 8), dim3(256), 0, stream>>>(
            raypos, raydir, tminmax, primpos, primrot, primscale, tmpl, nullptr, out, R);
    }
}